// Round 9
// baseline (156.199 us; speedup 1.0000x reference)
//
#include <hip/hip_runtime.h>
#include <hip/hip_fp16.h>

typedef _Float16 half8v __attribute__((ext_vector_type(8)));
typedef _Float16 half2v __attribute__((ext_vector_type(2)));
typedef float f32x4 __attribute__((ext_vector_type(4)));

// ---------------- prep kernel (1 block, runs once per launch) ----------------
// ws layout: [0,8192)      W frags : half wf[ks(2)][nt(4)][lane(64)][j(8)]
//            [8192,10240)  pvec frags: half pf[ks(2)][lane(64)][j(8)] (row 0 only)
//            [10240,13376) pair table: uint tbl[784] = (ri*72)<<16 | (ci*72)
__global__ void afm_prep(const float* __restrict__ W, const float* __restrict__ pvec,
                         unsigned char* __restrict__ ws) {
  const int tid = threadIdx.x;
  _Float16* wf = (_Float16*)ws;
  _Float16* pf = (_Float16*)(ws + 8192);
  unsigned int* tbl = (unsigned int*)(ws + 10240);
  for (int idx = tid; idx < 4096; idx += 256) {
    int j = idx & 7, lane = (idx >> 3) & 63, nt = (idx >> 9) & 3, ks = idx >> 11;
    int k = ks * 32 + (lane >> 4) * 8 + j;   // e index
    int u = nt * 16 + (lane & 15);           // u index
    wf[idx] = (_Float16)W[k * 64 + u];
  }
  for (int idx = tid; idx < 1024; idx += 256) {
    int j = idx & 7, lane = (idx >> 3) & 63, ks = idx >> 9;
    int k = ks * 32 + (lane >> 4) * 8 + j;
    pf[idx] = ((lane & 15) == 0) ? (_Float16)pvec[k] : (_Float16)0.f;
  }
  for (int p = tid; p < 784; p += 256) {
    int pc = p > 779 ? 779 : p;
    int i = 0, rem = pc;
    while (rem >= 39 - i) { rem -= 39 - i; ++i; }
    int j = i + 1 + rem;
    tbl[p] = ((unsigned)(i * 72) << 16) | (unsigned)(j * 72);
  }
}

#define ISSUE_READS(slot, offw)                                                    \
  do {                                                                             \
    const _Float16* xi_ = &xh[((offw) >> 16) + eoff];                              \
    const _Float16* xj_ = &xh[((offw) & 0xffffu) + eoff];                          \
    xia[slot][0] = *(const half8v*)xi_;                                            \
    xia[slot][1] = *(const half8v*)(xi_ + 32);                                     \
    xja[slot][0] = *(const half8v*)xj_;                                            \
    xja[slot][1] = *(const half8v*)(xj_ + 32);                                     \
  } while (0)

// ---------------- main kernel: one 8-wave block per batch row ----------------
// Transposed-V design (R8, measured 56 µs at 4 waves): D[u][pair] =
// mfma(W^T-frag, ip^T-frag); bias via MFMA C operand; lane-local relu-dot.
// This round: 8 waves (7 tiles/wave) for latency hiding + per-kg partials to
// LDS (part[784][4]) instead of 2 shfl_xor per tile.
// Phase-A loop MUST stay compile-time-unrolled, no data-dependent break
// (rule #20 — cost 20x in R5).
__global__ __launch_bounds__(512) void afm_main(
    const float* __restrict__ x, const float* __restrict__ bvec,
    const float* __restrict__ hvec, const unsigned char* __restrict__ ws,
    float* __restrict__ out) {
  // LDS: 5760 + 3136 + 12544 + 3136 + 96 = 24.7 KB
  __shared__ __align__(16) _Float16 xh[40 * 72];  // row stride 144 B
  __shared__ __align__(16) unsigned int tblu[784];
  __shared__ __align__(16) float part[784][4];    // per-kg score partials
  __shared__ float s2s[784];
  __shared__ float red[24];

  const int tid = threadIdx.x;
  const int b = blockIdx.x;
  const int lane = tid & 63;
  const int wid = tid >> 6;      // 0..7
  const int m = lane & 15, kg = lane >> 4;

  // ---- issue x[b] loads first (longest latency path) ----
  const float4* xg = (const float4*)(x + b * 2560);
  float4 v0 = xg[tid];
  float4 v1;
  if (tid < 128) v1 = xg[512 + tid];

  // ---- stage pair table -> LDS (196 float4s = 784 uints) ----
  {
    const float4* tg = (const float4*)(ws + 10240);
    float4* ts = (float4*)tblu;
    if (tid < 196) ts[tid] = tg[tid];
  }

  // ---- W/pvec fragments + bias/h float4s (L2-hot) ----
  const half8v* wfg = (const half8v*)ws;
  half8v wf[2][4];
#pragma unroll
  for (int ks = 0; ks < 2; ++ks)
#pragma unroll
    for (int nt = 0; nt < 4; ++nt) wf[ks][nt] = wfg[(ks * 4 + nt) * 64 + lane];
  const half8v* pfg = (const half8v*)(ws + 8192);
  half8v pf[2] = {pfg[lane], pfg[64 + lane]};
  f32x4 buv[4], huv[4];
#pragma unroll
  for (int nt = 0; nt < 4; ++nt) {
    buv[nt] = *(const f32x4*)&bvec[nt * 16 + kg * 4];   // bias for rows u=nt*16+kg*4+r
    huv[nt] = *(const f32x4*)&hvec[nt * 16 + kg * 4];
  }

  // ---- stage x -> LDS fp16 (row stride 72 halves) ----
  {
    int f = tid >> 4, e4 = tid & 15;
    half2v* dst = (half2v*)&xh[f * 72 + e4 * 4];
    dst[0] = __builtin_bit_cast(half2v, __builtin_amdgcn_cvt_pkrtz(v0.x, v0.y));
    dst[1] = __builtin_bit_cast(half2v, __builtin_amdgcn_cvt_pkrtz(v0.z, v0.w));
  }
  if (tid < 128) {
    int g = 512 + tid;
    int f = g >> 4, e4 = g & 15;
    half2v* dst = (half2v*)&xh[f * 72 + e4 * 4];
    dst[0] = __builtin_bit_cast(half2v, __builtin_amdgcn_cvt_pkrtz(v1.x, v1.y));
    dst[1] = __builtin_bit_cast(half2v, __builtin_amdgcn_cvt_pkrtz(v1.z, v1.w));
  }
  __syncthreads();

  // ---- phase A: 7 tile-slots/wave (49 tiles, clamped redo), 2-deep pipeline ----
  const int eoff = kg * 8;
  const f32x4 zv = (f32x4){0.f, 0.f, 0.f, 0.f};
  unsigned int off[2];
  half8v xia[2][2], xja[2][2];
  off[0] = tblu[16 * wid + m];            // tile i=0 (t=wid<=7)
  ISSUE_READS(0, off[0]);
  {
    int tn = wid + 8;
    tn = tn > 48 ? 48 : tn;
    off[1] = tblu[16 * tn + m];           // tile i=1
  }
#pragma unroll
  for (int i = 0; i < 7; ++i) {
    const int cur = i & 1, nxt = cur ^ 1;
    if (i < 6) ISSUE_READS(nxt, off[nxt]);
    if (i < 5) {
      int tn = wid + 8 * (i + 2);
      tn = tn > 48 ? 48 : tn;
      off[cur] = tblu[16 * tn + m];
    }
    half8v a0 = xia[cur][0] * xja[cur][0];   // ip^T frag, e = kg*8+j
    half8v a1 = xia[cur][1] * xja[cur][1];   // ip^T frag, e = 32+kg*8+j
    // V^T: D[u=nt*16+kg*4+r][pair=m]; bias folded via C operand (no movs)
    f32x4 acc[4];
#pragma unroll
    for (int nt = 0; nt < 4; ++nt) {
      acc[nt] = __builtin_amdgcn_mfma_f32_16x16x32_f16(wf[0][nt], a0, buv[nt], 0, 0, 0);
      acc[nt] = __builtin_amdgcn_mfma_f32_16x16x32_f16(wf[1][nt], a1, acc[nt], 0, 0, 0);
    }
    f32x4 accp = __builtin_amdgcn_mfma_f32_16x16x32_f16(pf[0], a0, zv, 0, 0, 0);
    accp = __builtin_amdgcn_mfma_f32_16x16x32_f16(pf[1], a1, accp, 0, 0, 0);

    // lane-local relu-dot over this lane's 16 u-values (4 independent chains)
    float sp0 = fmaxf(acc[0][0], 0.f) * huv[0][0];
    float sp1 = fmaxf(acc[1][0], 0.f) * huv[1][0];
    float sp2 = fmaxf(acc[2][0], 0.f) * huv[2][0];
    float sp3 = fmaxf(acc[3][0], 0.f) * huv[3][0];
#pragma unroll
    for (int r = 1; r < 4; ++r) {
      sp0 = fmaf(fmaxf(acc[0][r], 0.f), huv[0][r], sp0);
      sp1 = fmaf(fmaxf(acc[1][r], 0.f), huv[1][r], sp1);
      sp2 = fmaf(fmaxf(acc[2][r], 0.f), huv[2][r], sp2);
      sp3 = fmaf(fmaxf(acc[3][r], 0.f), huv[3][r], sp3);
    }
    float sp = (sp0 + sp1) + (sp2 + sp3);

    int tt = wid + 8 * i;
    tt = tt > 48 ? 48 : tt;
    part[16 * tt + m][kg] = sp;          // all 64 lanes; 2-way bank alias = free
    if (kg == 0) s2s[16 * tt + m] = accp[0];  // D[0][pair=m], 16-lane coalesced
  }
  __syncthreads();

  // ---- phase B: finish scores (float4), softmax over 780, weighted s2 ----
  const f32x4* part4 = (const f32x4*)part;
  const int p1 = tid + 512;
  f32x4 q0 = part4[tid];
  float s0 = (q0[0] + q0[1]) + (q0[2] + q0[3]);
  float s1 = -1e30f;
  if (p1 < 780) {
    f32x4 q1 = part4[p1];
    s1 = (q1[0] + q1[1]) + (q1[2] + q1[3]);
  }
  float mx = fmaxf(s0, s1);
#pragma unroll
  for (int o = 32; o; o >>= 1) mx = fmaxf(mx, __shfl_xor(mx, o));
  if (lane == 0) red[wid] = mx;
  __syncthreads();
  mx = red[0];
#pragma unroll
  for (int w = 1; w < 8; ++w) mx = fmaxf(mx, red[w]);
  float e0 = __expf(s0 - mx);
  float num = e0 * s2s[tid];
  float den = e0;
  if (p1 < 780) {
    float e1 = __expf(s1 - mx);
    num += e1 * s2s[p1];
    den += e1;
  }
#pragma unroll
  for (int o = 32; o; o >>= 1) {
    num += __shfl_xor(num, o);
    den += __shfl_xor(den, o);
  }
  if (lane == 0) { red[8 + wid] = num; red[16 + wid] = den; }
  __syncthreads();
  if (tid == 0) {
    float ns = 0.f, ds = 0.f;
#pragma unroll
    for (int w = 0; w < 8; ++w) { ns += red[8 + w]; ds += red[16 + w]; }
    out[b] = ns / ds;
  }
}

extern "C" void kernel_launch(void* const* d_in, const int* in_sizes, int n_in,
                              void* d_out, int out_size, void* d_ws, size_t ws_size,
                              hipStream_t stream) {
  const float* x    = (const float*)d_in[0];  // [4096,40,64]
  const float* W    = (const float*)d_in[1];  // [64,64]
  const float* bvec = (const float*)d_in[2];  // [64]
  const float* hvec = (const float*)d_in[3];  // [64,1]
  const float* pvec = (const float*)d_in[4];  // [64,1]
  float* out = (float*)d_out;                 // [4096,1]
  unsigned char* ws = (unsigned char*)d_ws;   // needs 13.4 KB

  hipLaunchKernelGGL(afm_prep, dim3(1), dim3(256), 0, stream, W, pvec, ws);
  hipLaunchKernelGGL(afm_main, dim3(4096), dim3(512), 0, stream,
                     x, bvec, hvec, ws, out);
}

// Round 10
// 128.866 us; speedup vs baseline: 1.2121x; 1.2121x over previous
//
#include <hip/hip_runtime.h>
#include <hip/hip_fp16.h>

typedef _Float16 half8v __attribute__((ext_vector_type(8)));
typedef _Float16 half2v __attribute__((ext_vector_type(2)));
typedef float f32x4 __attribute__((ext_vector_type(4)));

// ---------------- prep kernel (1 block, runs once per launch) ----------------
// ws layout: [0,8192)      W frags : half wf[ks(2)][nt(4)][lane(64)][j(8)]
//            [8192,10240)  pvec frags: half pf[ks(2)][lane(64)][j(8)] (row 0 only)
//            [10240,13376) pair table: uint tbl[784] = (ri*72)<<16 | (ci*72)
__global__ void afm_prep(const float* __restrict__ W, const float* __restrict__ pvec,
                         unsigned char* __restrict__ ws) {
  const int tid = threadIdx.x;
  _Float16* wf = (_Float16*)ws;
  _Float16* pf = (_Float16*)(ws + 8192);
  unsigned int* tbl = (unsigned int*)(ws + 10240);
  for (int idx = tid; idx < 4096; idx += 256) {
    int j = idx & 7, lane = (idx >> 3) & 63, nt = (idx >> 9) & 3, ks = idx >> 11;
    int k = ks * 32 + (lane >> 4) * 8 + j;   // e index
    int u = nt * 16 + (lane & 15);           // u index
    wf[idx] = (_Float16)W[k * 64 + u];
  }
  for (int idx = tid; idx < 1024; idx += 256) {
    int j = idx & 7, lane = (idx >> 3) & 63, ks = idx >> 9;
    int k = ks * 32 + (lane >> 4) * 8 + j;
    pf[idx] = ((lane & 15) == 0) ? (_Float16)pvec[k] : (_Float16)0.f;
  }
  for (int p = tid; p < 784; p += 256) {
    int pc = p > 779 ? 779 : p;
    int i = 0, rem = pc;
    while (rem >= 39 - i) { rem -= 39 - i; ++i; }
    int j = i + 1 + rem;
    tbl[p] = ((unsigned)(i * 72) << 16) | (unsigned)(j * 72);
  }
}

#define ISSUE_READS(slot, offw)                                                    \
  do {                                                                             \
    const _Float16* xi_ = &xh[((offw) >> 16) + eoff];                              \
    const _Float16* xj_ = &xh[((offw) & 0xffffu) + eoff];                          \
    xia[slot][0] = *(const half8v*)xi_;                                            \
    xia[slot][1] = *(const half8v*)(xi_ + 32);                                     \
    xja[slot][0] = *(const half8v*)xj_;                                            \
    xja[slot][1] = *(const half8v*)(xj_ + 32);                                     \
  } while (0)

// ---------------- main kernel: 4-wave block, TWO batch rows per block --------
// R8 transposed-V structure (measured 56 µs): D[u][pair] = mfma(W^T, ip^T);
// bias via MFMA C operand; lane-local relu-dot + 2 shfl_xor.
// This round: 2 batches/block (grid 2048) — one prologue (fragments, table,
// barriers) amortized over 2x phase-A work (25 tile-slots/wave vs 13).
// Batch-1 tiles use xh offset +2880 halves, folded into the packed pair
// offsets (+0x0B400B40). Phase-A loop: compile-time trip count 25, clamped
// redo of tile 97, NO data-dependent break (rule #20 — 20x cost in R5).
__global__ __launch_bounds__(256) void afm_main(
    const float* __restrict__ x, const float* __restrict__ bvec,
    const float* __restrict__ hvec, const unsigned char* __restrict__ ws,
    float* __restrict__ out) {
  // LDS: 11520 + 3136 + 6272 + 6272 + 96 = 27.3 KB -> 5 blocks/CU cap
  __shared__ __align__(16) _Float16 xh[80 * 72];   // 2 batches, row stride 144 B
  __shared__ __align__(16) unsigned int tblu[784];
  __shared__ float scs[1568];
  __shared__ float s2s[1568];
  __shared__ float red[24];

  const int tid = threadIdx.x;
  const int b = blockIdx.x;                        // handles rows 2b, 2b+1
  const int lane = tid & 63;
  const int wid = tid >> 6;      // 0..3
  const int m = lane & 15, kg = lane >> 4;

  // ---- issue both x rows' loads first (longest latency path) ----
  const float4* xg = (const float4*)(x + b * 5120);
  float4 v0 = xg[tid];
  float4 v1 = xg[256 + tid];
  float4 v2 = xg[512 + tid];
  float4 v3 = xg[768 + tid];
  float4 v4 = xg[1024 + tid];

  // ---- stage pair table -> LDS (196 float4s = 784 uints) ----
  {
    const float4* tg = (const float4*)(ws + 10240);
    float4* ts = (float4*)tblu;
    if (tid < 196) ts[tid] = tg[tid];
  }

  // ---- W/pvec fragments + bias/h float4s (L2-hot) ----
  const half8v* wfg = (const half8v*)ws;
  half8v wf[2][4];
#pragma unroll
  for (int ks = 0; ks < 2; ++ks)
#pragma unroll
    for (int nt = 0; nt < 4; ++nt) wf[ks][nt] = wfg[(ks * 4 + nt) * 64 + lane];
  const half8v* pfg = (const half8v*)(ws + 8192);
  half8v pf[2] = {pfg[lane], pfg[64 + lane]};
  f32x4 buv[4], huv[4];
#pragma unroll
  for (int nt = 0; nt < 4; ++nt) {
    buv[nt] = *(const f32x4*)&bvec[nt * 16 + kg * 4];   // bias for rows u=nt*16+kg*4+r
    huv[nt] = *(const f32x4*)&hvec[nt * 16 + kg * 4];
  }

  // ---- stage x -> LDS fp16 (rows f=0..79 contiguous across both batches) ----
#define STAGE_X(vv, base)                                                          \
  do {                                                                             \
    int g = (base) + tid;                                                          \
    int f = g >> 4, e4 = g & 15;                                                   \
    half2v* dst = (half2v*)&xh[f * 72 + e4 * 4];                                   \
    dst[0] = __builtin_bit_cast(half2v, __builtin_amdgcn_cvt_pkrtz((vv).x, (vv).y)); \
    dst[1] = __builtin_bit_cast(half2v, __builtin_amdgcn_cvt_pkrtz((vv).z, (vv).w)); \
  } while (0)
  STAGE_X(v0, 0);
  STAGE_X(v1, 256);
  STAGE_X(v2, 512);
  STAGE_X(v3, 768);
  STAGE_X(v4, 1024);
#undef STAGE_X
  __syncthreads();

  // ---- phase A: 25 tile-slots/wave (98 tiles over 4 waves), 2-deep pipeline ----
  const int eoff = kg * 8;
  const f32x4 zv = (f32x4){0.f, 0.f, 0.f, 0.f};
  unsigned int off[2];
  half8v xia[2][2], xja[2][2];
  off[0] = tblu[16 * wid + m];            // slot 0: t=wid<=3, batch 0
  ISSUE_READS(0, off[0]);
  off[1] = tblu[16 * (wid + 4) + m];      // slot 1: t<=7, batch 0
#pragma unroll
  for (int i = 0; i < 25; ++i) {
    const int cur = i & 1, nxt = cur ^ 1;
    if (i < 24) ISSUE_READS(nxt, off[nxt]);
    if (i < 23) {
      int tn = wid + 4 * (i + 2);
      tn = tn > 97 ? 97 : tn;              // last tile = batch1, tt=48
      int bn = tn >= 49;
      int ttn = tn - (bn ? 49 : 0);
      unsigned o = tblu[16 * ttn + m];
      off[cur] = o + (bn ? 0x0B400B40u : 0u);   // +2880 halves on both offsets
    }
    half8v a0 = xia[cur][0] * xja[cur][0];   // ip^T frag, e = kg*8+j
    half8v a1 = xia[cur][1] * xja[cur][1];   // ip^T frag, e = 32+kg*8+j
    // V^T: D[u=nt*16+kg*4+r][pair=m]; bias folded via C operand (no movs)
    f32x4 acc[4];
#pragma unroll
    for (int nt = 0; nt < 4; ++nt) {
      acc[nt] = __builtin_amdgcn_mfma_f32_16x16x32_f16(wf[0][nt], a0, buv[nt], 0, 0, 0);
      acc[nt] = __builtin_amdgcn_mfma_f32_16x16x32_f16(wf[1][nt], a1, acc[nt], 0, 0, 0);
    }
    f32x4 accp = __builtin_amdgcn_mfma_f32_16x16x32_f16(pf[0], a0, zv, 0, 0, 0);
    accp = __builtin_amdgcn_mfma_f32_16x16x32_f16(pf[1], a1, accp, 0, 0, 0);

    // lane-local relu-dot over this lane's 16 u-values (4 independent chains)
    float sp0 = fmaxf(acc[0][0], 0.f) * huv[0][0];
    float sp1 = fmaxf(acc[1][0], 0.f) * huv[1][0];
    float sp2 = fmaxf(acc[2][0], 0.f) * huv[2][0];
    float sp3 = fmaxf(acc[3][0], 0.f) * huv[3][0];
#pragma unroll
    for (int r = 1; r < 4; ++r) {
      sp0 = fmaf(fmaxf(acc[0][r], 0.f), huv[0][r], sp0);
      sp1 = fmaf(fmaxf(acc[1][r], 0.f), huv[1][r], sp1);
      sp2 = fmaf(fmaxf(acc[2][r], 0.f), huv[2][r], sp2);
      sp3 = fmaf(fmaxf(acc[3][r], 0.f), huv[3][r], sp3);
    }
    float s = (sp0 + sp1) + (sp2 + sp3);
    // reduce over the 4 kg groups (lanes m, m+16, m+32, m+48)
    s += __shfl_xor(s, 16);
    s += __shfl_xor(s, 32);

    int t = wid + 4 * i;
    t = t > 97 ? 97 : t;                   // clamped redo: identical value, benign
    int bt = t >= 49;
    int tt = t - (bt ? 49 : 0);
    if (kg == 0) {                         // 16 lanes, coalesced 16-float rows
      int idx = (bt ? 784 : 0) + 16 * tt + m;
      scs[idx] = s;
      s2s[idx] = accp[0];                  // D[0][pair=m] lives in reg 0 of kg==0
    }
  }
  __syncthreads();

  // ---- phase B: two independent softmaxes over 780 + weighted s2 sums ----
  float sv0[4], sv1[4];
  float mx0 = -1e30f, mx1 = -1e30f;
#pragma unroll
  for (int k2 = 0; k2 < 4; ++k2) {
    int p = tid + k2 * 256;
    if (p < 780) {
      sv0[k2] = scs[p];
      sv1[k2] = scs[784 + p];
      mx0 = fmaxf(mx0, sv0[k2]);
      mx1 = fmaxf(mx1, sv1[k2]);
    } else {
      sv0[k2] = -1e30f;
      sv1[k2] = -1e30f;
    }
  }
#pragma unroll
  for (int o = 32; o; o >>= 1) {
    mx0 = fmaxf(mx0, __shfl_xor(mx0, o));
    mx1 = fmaxf(mx1, __shfl_xor(mx1, o));
  }
  if (lane == 0) { red[wid] = mx0; red[4 + wid] = mx1; }
  __syncthreads();
  mx0 = fmaxf(fmaxf(red[0], red[1]), fmaxf(red[2], red[3]));
  mx1 = fmaxf(fmaxf(red[4], red[5]), fmaxf(red[6], red[7]));
  float num0 = 0.f, den0 = 0.f, num1 = 0.f, den1 = 0.f;
#pragma unroll
  for (int k2 = 0; k2 < 4; ++k2) {
    int p = tid + k2 * 256;
    if (p < 780) {
      float e0 = __expf(sv0[k2] - mx0);
      num0 += e0 * s2s[p];
      den0 += e0;
      float e1 = __expf(sv1[k2] - mx1);
      num1 += e1 * s2s[784 + p];
      den1 += e1;
    }
  }
#pragma unroll
  for (int o = 32; o; o >>= 1) {
    num0 += __shfl_xor(num0, o);
    den0 += __shfl_xor(den0, o);
    num1 += __shfl_xor(num1, o);
    den1 += __shfl_xor(den1, o);
  }
  if (lane == 0) {
    red[8 + wid] = num0;  red[12 + wid] = den0;
    red[16 + wid] = num1; red[20 + wid] = den1;
  }
  __syncthreads();
  if (tid == 0) {
    out[2 * b] = (red[8] + red[9] + red[10] + red[11]) /
                 (red[12] + red[13] + red[14] + red[15]);
    out[2 * b + 1] = (red[16] + red[17] + red[18] + red[19]) /
                     (red[20] + red[21] + red[22] + red[23]);
  }
}

extern "C" void kernel_launch(void* const* d_in, const int* in_sizes, int n_in,
                              void* d_out, int out_size, void* d_ws, size_t ws_size,
                              hipStream_t stream) {
  const float* x    = (const float*)d_in[0];  // [4096,40,64]
  const float* W    = (const float*)d_in[1];  // [64,64]
  const float* bvec = (const float*)d_in[2];  // [64]
  const float* hvec = (const float*)d_in[3];  // [64,1]
  const float* pvec = (const float*)d_in[4];  // [64,1]
  float* out = (float*)d_out;                 // [4096,1]
  unsigned char* ws = (unsigned char*)d_ws;   // needs 13.4 KB

  hipLaunchKernelGGL(afm_prep, dim3(1), dim3(256), 0, stream, W, pvec, ws);
  hipLaunchKernelGGL(afm_main, dim3(2048), dim3(256), 0, stream,
                     x, bvec, hvec, ws, out);
}